// Round 5
// baseline (417.328 us; speedup 1.0000x reference)
//
#include <hip/hip_runtime.h>
#include <cstdint>

#define VOCAB   32000
#define HIDDEN  512
#define BATCH   256
#define SEQLEN  128

typedef _Float16 f16;
typedef _Float16 f16x2 __attribute__((ext_vector_type(2)));
typedef _Float16 f16x4 __attribute__((ext_vector_type(4)));
typedef _Float16 f16x8 __attribute__((ext_vector_type(8)));
typedef float    f32x4 __attribute__((ext_vector_type(4)));

// ---------------------------------------------------------------------------
// ws layout (f16 copies, written every call since ws is re-poisoned):
//   emb16 : VOCAB*HIDDEN  f16 @ 0          (32,768,000 B)
//   wih16 : HIDDEN*HIDDEN f16 @ 32,768,000 (524,288 B)
//   whh16 : HIDDEN*HIDDEN f16 @ 33,292,288 (524,288 B)
// ---------------------------------------------------------------------------

// ---------------- Phase 0: f32 -> f16 convert (memory-bound) ----------------
__global__ __launch_bounds__(256) void conv_f16_kernel(
    const float* __restrict__ emb, const float* __restrict__ wih,
    const float* __restrict__ whh, f16* __restrict__ emb16,
    f16* __restrict__ wih16, f16* __restrict__ whh16)
{
  const long long EMB_N = (long long)VOCAB * HIDDEN;   // 16,384,000
  const long long W_N   = (long long)HIDDEN * HIDDEN;  // 262,144
  long long idx = ((long long)blockIdx.x * blockDim.x + threadIdx.x) * 4;
  const float* src; f16* dst; long long off;
  if (idx < EMB_N)            { src = emb; dst = emb16; off = idx; }
  else if (idx < EMB_N + W_N) { src = wih; dst = wih16; off = idx - EMB_N; }
  else                        { src = whh; dst = whh16; off = idx - EMB_N - W_N; }
  float4 v = *(const float4*)(src + off);
  f16x4 o = { (f16)v.x, (f16)v.y, (f16)v.z, (f16)v.w };
  *(f16x4*)(dst + off) = o;
}

// ---------------- Phase 1: x_proj = gather(emb) @ W_ih^T + b_ih -------------
// M=32768 (tokens), N=512, K=512. NT GEMM (both operands K-contiguous).
// LDS-free: each wave computes a 64x64 output tile, fragments loaded straight
// from global (16 B/lane contiguous), L2 provides reuse. 4 waves -> 128x128/WG.
// mfma_f32_16x16x32_f16: A-frag lane: row=lane&15, k=(lane>>4)*8 + e (contig)
//                        B-frag lane: col=lane&15, same k  (W row-major [N][K])
//                        D: col=lane&15, row=(lane>>4)*4 + j   [verified m89/m91]
__global__ __launch_bounds__(256) void xproj_kernel(
    const int*   __restrict__ tokens,   // [BATCH*SEQLEN]
    const f16*   __restrict__ emb16,    // [VOCAB][HIDDEN]
    const f16*   __restrict__ wih16,    // [HIDDEN][HIDDEN]  (row i = W_ih[i,:])
    const float* __restrict__ b_ih,     // [HIDDEN]
    float*       __restrict__ out)      // [32768][512]  (d_out, overwritten later)
{
  const int lane = threadIdx.x & 63;
  const int wave = threadIdx.x >> 6;                 // 0..3
  const int m0 = blockIdx.y * 128 + (wave >> 1) * 64;
  const int n0 = blockIdx.x * 128 + (wave & 1) * 64;
  const int lr = lane & 15;
  const int lg = lane >> 4;

  const f16* aptr[4];
  const f16* bptr[4];
#pragma unroll
  for (int mi = 0; mi < 4; ++mi) {
    int row = m0 + mi * 16 + lr;
    int tok = tokens[row];
    aptr[mi] = emb16 + (long long)tok * HIDDEN;
  }
#pragma unroll
  for (int ni = 0; ni < 4; ++ni) {
    int col = n0 + ni * 16 + lr;
    bptr[ni] = wih16 + (long long)col * HIDDEN;
  }

  f32x4 acc[4][4];
#pragma unroll
  for (int ni = 0; ni < 4; ++ni) {
    float b = b_ih[n0 + ni * 16 + lr];               // bias depends on col only
#pragma unroll
    for (int mi = 0; mi < 4; ++mi) acc[mi][ni] = (f32x4){b, b, b, b};
  }

  for (int kt = 0; kt < 16; ++kt) {
    const int kb = kt * 32 + lg * 8;
    f16x8 af[4], bf[4];
#pragma unroll
    for (int mi = 0; mi < 4; ++mi) af[mi] = *(const f16x8*)(aptr[mi] + kb);
#pragma unroll
    for (int ni = 0; ni < 4; ++ni) bf[ni] = *(const f16x8*)(bptr[ni] + kb);
#pragma unroll
    for (int mi = 0; mi < 4; ++mi)
#pragma unroll
      for (int ni = 0; ni < 4; ++ni)
        acc[mi][ni] = __builtin_amdgcn_mfma_f32_16x16x32_f16(
            af[mi], bf[ni], acc[mi][ni], 0, 0, 0);
  }

#pragma unroll
  for (int mi = 0; mi < 4; ++mi)
#pragma unroll
    for (int ni = 0; ni < 4; ++ni)
#pragma unroll
      for (int j = 0; j < 4; ++j) {
        int rg = m0 + mi * 16 + lg * 4 + j;
        int cg = n0 + ni * 16 + lr;
        out[(long long)rg * HIDDEN + cg] = acc[mi][ni][j];
      }
}

// ---------------- Phase 2: sequential recurrence ----------------------------
// 256 WGs (one batch row each), 1024 threads. thread = (i = tid&511, q = tid>>9):
// owns output row i, j-half q*256..+256 (128 f16 pairs of W_hh[i,:]).
// W_hh f16 residency: 96 pairs in VGPRs + 32 pairs in LDS (128 KB) per thread.
// h kept as packed-f16 pairs in LDS (wave-uniform broadcast reads).
// Inner product: v_dot2_f32_f16 (1 VALU op per packed pair, f32 accumulate).
__device__ __forceinline__ float dp2(uint32_t w, uint32_t h, float acc) {
  f16x2 wv = __builtin_bit_cast(f16x2, w);
  f16x2 hv = __builtin_bit_cast(f16x2, h);
#if __has_builtin(__builtin_amdgcn_fdot2)
  return __builtin_amdgcn_fdot2(wv, hv, acc, false);   // v_dot2_f32_f16
#else
  acc = fmaf((float)wv.x, (float)hv.x, acc);           // v_fma_mix_f32 fallback
  acc = fmaf((float)wv.y, (float)hv.y, acc);
  return acc;
#endif
}

__global__ __launch_bounds__(1024) void rnn_kernel(
    const f16*   __restrict__ whh16,  // [512][512]
    const float* __restrict__ b_hh,   // [512]
    const float* __restrict__ h0,     // [BATCH][512] initial hidden
    float*       __restrict__ out,    // [BATCH][SEQLEN][512] xp in, h out (in-place)
    float*       __restrict__ hfin)   // [BATCH][512]
{
  extern __shared__ char smem[];
  uint4* hh4  = (uint4*)smem;                        // 64 uint4  (256 h-pairs f16)
  float* pacc = (float*)(smem + 1024);               // 1024 f32 partials
  uint4* ldsW = (uint4*)(smem + 1024 + 4096);        // 8*1024 uint4 = 128 KB

  const int tid = threadIdx.x;
  const int q   = tid >> 9;        // 0..1  (wave-uniform: waves 0-7 q=0, 8-15 q=1)
  const int i   = tid & 511;
  const int b   = blockIdx.x;

  // --- load this thread's W_hh[i, q*256 .. q*256+255] as 32 uint4 chunks ---
  const uint4* wrow = (const uint4*)(whh16 + ((long long)i * HIDDEN + q * 256));
  uint32_t wreg[96];
#pragma unroll
  for (int c = 0; c < 24; ++c) {
    uint4 v = wrow[c];
    wreg[4 * c + 0] = v.x; wreg[4 * c + 1] = v.y;
    wreg[4 * c + 2] = v.z; wreg[4 * c + 3] = v.w;
  }
#pragma unroll
  for (int c = 0; c < 8; ++c) ldsW[c * 1024 + tid] = wrow[24 + c];

  // init h from h0 (zeros in practice, but honor the input)
  if (q == 0) ((f16*)hh4)[i] = (f16)h0[(long long)b * HIDDEN + i];
  const float bh = b_hh[i];
  __syncthreads();

  float* xprow = out + (long long)b * SEQLEN * HIDDEN;
  float xpn = xprow[i];                       // prefetch xp(t=0)

  for (int t = 0; t < SEQLEN; ++t) {
    const float xpv = xpn;
    const int tn = (t < SEQLEN - 1) ? t + 1 : t;
    xpn = xprow[tn * HIDDEN + i];             // prefetch next step's xp early

    float a0 = 0.f, a1 = 0.f, a2 = 0.f, a3 = 0.f;
#pragma unroll
    for (int c = 0; c < 24; ++c) {            // register-resident W part
      uint4 hv = hh4[q * 32 + c];             // wave-uniform broadcast read
      a0 = dp2(wreg[4 * c + 0], hv.x, a0);
      a1 = dp2(wreg[4 * c + 1], hv.y, a1);
      a2 = dp2(wreg[4 * c + 2], hv.z, a2);
      a3 = dp2(wreg[4 * c + 3], hv.w, a3);
    }
#pragma unroll
    for (int c = 0; c < 8; ++c) {             // LDS-resident W part
      uint4 hv = hh4[q * 32 + 24 + c];
      uint4 wv = ldsW[c * 1024 + tid];
      a0 = dp2(wv.x, hv.x, a0);
      a1 = dp2(wv.y, hv.y, a1);
      a2 = dp2(wv.z, hv.z, a2);
      a3 = dp2(wv.w, hv.w, a3);
    }
    pacc[tid] = (a0 + a1) + (a2 + a3);
    __syncthreads();

    if (q == 0) {
      float pre = xpv + bh + pacc[i] + pacc[i + 512];
      float h = tanhf(pre);
      xprow[t * HIDDEN + i] = h;              // overwrite xp with output h
      ((f16*)hh4)[i] = (f16)h;                // h for next step (packed f16)
      if (t == SEQLEN - 1) hfin[(long long)b * HIDDEN + i] = h;
    }
    __syncthreads();
  }
}

// ---------------------------------------------------------------------------
extern "C" void kernel_launch(void* const* d_in, const int* in_sizes, int n_in,
                              void* d_out, int out_size, void* d_ws, size_t ws_size,
                              hipStream_t stream) {
  const int*   tokens = (const int*)  d_in[0];
  const float* hidden = (const float*)d_in[1];
  const float* emb    = (const float*)d_in[2];
  const float* wih    = (const float*)d_in[3];
  const float* whh    = (const float*)d_in[4];
  const float* bih    = (const float*)d_in[5];
  const float* bhh    = (const float*)d_in[6];
  float* out = (float*)d_out;

  f16* emb16 = (f16*)d_ws;
  f16* wih16 = (f16*)((char*)d_ws + 32768000);
  f16* whh16 = (f16*)((char*)d_ws + 33292288);

  // Phase 0: convert emb/W_ih/W_hh to f16 (16,908,288 elems / 4 per thread)
  conv_f16_kernel<<<16512, 256, 0, stream>>>(emb, wih, whh, emb16, wih16, whh16);

  // Phase 1: x_proj into d_out (in-place consumed by phase 2)
  xproj_kernel<<<dim3(4, 256), 256, 0, stream>>>(tokens, emb16, wih16, bih, out);

  // Phase 2: recurrence (136,192 B dynamic LDS > 64 KB default -> opt in)
  const int LDSB = 1024 + 4096 + 131072;
  hipFuncSetAttribute((const void*)rnn_kernel,
                      hipFuncAttributeMaxDynamicSharedMemorySize, LDSB);
  rnn_kernel<<<BATCH, 1024, LDSB, stream>>>(
      whh16, bhh, hidden, out, out + (long long)BATCH * SEQLEN * HIDDEN);
}

// Round 6
// 399.248 us; speedup vs baseline: 1.0453x; 1.0453x over previous
//
#include <hip/hip_runtime.h>
#include <cstdint>

#define VOCAB   32000
#define HIDDEN  512
#define BATCH   256
#define SEQLEN  128

typedef _Float16 f16;
typedef _Float16 f16x2 __attribute__((ext_vector_type(2)));
typedef _Float16 f16x4 __attribute__((ext_vector_type(4)));
typedef _Float16 f16x8 __attribute__((ext_vector_type(8)));
typedef float    f32x4 __attribute__((ext_vector_type(4)));

// ---------------------------------------------------------------------------
// ws layout (f16 copies, written every call since ws is re-poisoned):
//   emb16 : VOCAB*HIDDEN  f16 @ 0          (32,768,000 B)
//   wih16 : HIDDEN*HIDDEN f16 @ 32,768,000 (524,288 B)
//   whh16 : HIDDEN*HIDDEN f16 @ 33,292,288 (524,288 B)
// ---------------------------------------------------------------------------

// ---------------- Phase 0: f32 -> f16 convert (memory-bound) ----------------
__global__ __launch_bounds__(256) void conv_f16_kernel(
    const float* __restrict__ emb, const float* __restrict__ wih,
    const float* __restrict__ whh, f16* __restrict__ emb16,
    f16* __restrict__ wih16, f16* __restrict__ whh16)
{
  const long long EMB_N = (long long)VOCAB * HIDDEN;   // 16,384,000
  const long long W_N   = (long long)HIDDEN * HIDDEN;  // 262,144
  long long idx = ((long long)blockIdx.x * blockDim.x + threadIdx.x) * 4;
  const float* src; f16* dst; long long off;
  if (idx < EMB_N)            { src = emb; dst = emb16; off = idx; }
  else if (idx < EMB_N + W_N) { src = wih; dst = wih16; off = idx - EMB_N; }
  else                        { src = whh; dst = whh16; off = idx - EMB_N - W_N; }
  float4 v = *(const float4*)(src + off);
  f16x4 o = { (f16)v.x, (f16)v.y, (f16)v.z, (f16)v.w };
  *(f16x4*)(dst + off) = o;
}

// ---------------- Phase 1: x_proj = gather(emb) @ W_ih^T + b_ih -------------
// (unchanged this round — keep the rnn delta clean; profile will expose its
//  true cost once rnn shrinks below it)
__global__ __launch_bounds__(256) void xproj_kernel(
    const int*   __restrict__ tokens,   // [BATCH*SEQLEN]
    const f16*   __restrict__ emb16,    // [VOCAB][HIDDEN]
    const f16*   __restrict__ wih16,    // [HIDDEN][HIDDEN]
    const float* __restrict__ b_ih,     // [HIDDEN]
    float*       __restrict__ out)      // [32768][512]
{
  const int lane = threadIdx.x & 63;
  const int wave = threadIdx.x >> 6;
  const int m0 = blockIdx.y * 128 + (wave >> 1) * 64;
  const int n0 = blockIdx.x * 128 + (wave & 1) * 64;
  const int lr = lane & 15;
  const int lg = lane >> 4;

  const f16* aptr[4];
  const f16* bptr[4];
#pragma unroll
  for (int mi = 0; mi < 4; ++mi) {
    int row = m0 + mi * 16 + lr;
    int tok = tokens[row];
    aptr[mi] = emb16 + (long long)tok * HIDDEN;
  }
#pragma unroll
  for (int ni = 0; ni < 4; ++ni) {
    int col = n0 + ni * 16 + lr;
    bptr[ni] = wih16 + (long long)col * HIDDEN;
  }

  f32x4 acc[4][4];
#pragma unroll
  for (int ni = 0; ni < 4; ++ni) {
    float b = b_ih[n0 + ni * 16 + lr];
#pragma unroll
    for (int mi = 0; mi < 4; ++mi) acc[mi][ni] = (f32x4){b, b, b, b};
  }

  for (int kt = 0; kt < 16; ++kt) {
    const int kb = kt * 32 + lg * 8;
    f16x8 af[4], bf[4];
#pragma unroll
    for (int mi = 0; mi < 4; ++mi) af[mi] = *(const f16x8*)(aptr[mi] + kb);
#pragma unroll
    for (int ni = 0; ni < 4; ++ni) bf[ni] = *(const f16x8*)(bptr[ni] + kb);
#pragma unroll
    for (int mi = 0; mi < 4; ++mi)
#pragma unroll
      for (int ni = 0; ni < 4; ++ni)
        acc[mi][ni] = __builtin_amdgcn_mfma_f32_16x16x32_f16(
            af[mi], bf[ni], acc[mi][ni], 0, 0, 0);
  }

#pragma unroll
  for (int mi = 0; mi < 4; ++mi)
#pragma unroll
    for (int ni = 0; ni < 4; ++ni)
#pragma unroll
      for (int j = 0; j < 4; ++j) {
        int rg = m0 + mi * 16 + lg * 4 + j;
        int cg = n0 + ni * 16 + lr;
        out[(long long)rg * HIDDEN + cg] = acc[mi][ni][j];
      }
}

// ---------------- Phase 2: sequential recurrence (O=4 x S=8 tiling) ---------
// 256 WGs (one batch row), 1024 threads. wave w (0..15), lane l (0..63):
//   s  = w>>1          col-slice 0..7, wave-uniform -> h reads are broadcast
//   ib = (w&1)*64 + l  row-group 0..127
// Thread owns rows {ib, ib+128, ib+256, ib+384}, cols [s*64, s*64+64):
//   4 x 64 f16 = 128 words: rows o=0..2 in wreg[96] (VGPR), o=3 in LDS.
// h-broadcast reads: 8 ds_read_b128/step (was 32) + 8 for the LDS W part.
__device__ __forceinline__ float dp2(uint32_t w, uint32_t h, float acc) {
  f16x2 wv = __builtin_bit_cast(f16x2, w);
  f16x2 hv = __builtin_bit_cast(f16x2, h);
#if __has_builtin(__builtin_amdgcn_fdot2)
  return __builtin_amdgcn_fdot2(wv, hv, acc, false);   // v_dot2_f32_f16
#else
  acc = fmaf((float)wv.x, (float)hv.x, acc);
  acc = fmaf((float)wv.y, (float)hv.y, acc);
  return acc;
#endif
}

__global__ __launch_bounds__(1024, 4) void rnn_kernel(
    const f16*   __restrict__ whh16,  // [512][512]
    const float* __restrict__ b_hh,   // [512]
    const float* __restrict__ h0,     // [BATCH][512]
    float*       __restrict__ out,    // [BATCH][SEQLEN][512] xp in, h out
    float*       __restrict__ hfin)   // [BATCH][512]
{
  extern __shared__ char smem[];
  uint4* hh4  = (uint4*)smem;                        // 64 uint4 (512 h f16) 1 KB
  float* pacc = (float*)(smem + 1024);               // [s=8][r=512] f32 = 16 KB
  uint4* ldsW = (uint4*)(smem + 1024 + 16384);       // 8*1024 uint4 = 128 KB

  const int tid = threadIdx.x;
  const int w   = tid >> 6;
  const int l   = tid & 63;
  const int s   = w >> 1;              // wave-uniform col-slice
  const int ib  = (w & 1) * 64 + l;    // 0..127
  const int b   = blockIdx.x;

  // --- W residency: rows ib+o*128, cols s*64.. ; o=0..2 -> VGPR, o=3 -> LDS
  uint32_t wreg[96];
#pragma unroll
  for (int o = 0; o < 3; ++o) {
    const uint4* wr = (const uint4*)(whh16 + ((long long)(ib + o * 128) * HIDDEN + s * 64));
#pragma unroll
    for (int c = 0; c < 8; ++c) {
      uint4 v = wr[c];
      wreg[o * 32 + c * 4 + 0] = v.x; wreg[o * 32 + c * 4 + 1] = v.y;
      wreg[o * 32 + c * 4 + 2] = v.z; wreg[o * 32 + c * 4 + 3] = v.w;
    }
  }
  {
    const uint4* wr3 = (const uint4*)(whh16 + ((long long)(ib + 384) * HIDDEN + s * 64));
#pragma unroll
    for (int c = 0; c < 8; ++c) ldsW[c * 1024 + tid] = wr3[c];
  }

  // --- h init + per-reducer constants (threads 0..511 are reducers)
  if (tid < 512) ((f16*)hh4)[tid] = (f16)h0[(long long)b * HIDDEN + tid];
  const float bh = (tid < 512) ? b_hh[tid] : 0.f;
  float* xprow = out + (long long)b * SEQLEN * HIDDEN;
  float xpn = (tid < 512) ? xprow[tid] : 0.f;        // prefetch xp(t=0)
  __syncthreads();

  for (int t = 0; t < SEQLEN; ++t) {
    const float xpv = xpn;
    const int tn = (t < SEQLEN - 1) ? t + 1 : t;
    if (tid < 512) xpn = xprow[tn * HIDDEN + tid];   // hide HBM latency under dots

    float a0 = 0.f, a1 = 0.f, a2 = 0.f, a3 = 0.f;
#pragma unroll
    for (int hc = 0; hc < 8; ++hc) {
      uint4 hv = hh4[s * 8 + hc];                    // broadcast (uniform addr)
      uint4 w3 = ldsW[hc * 1024 + tid];              // 16B/lane contiguous
      a0 = dp2(wreg[0 * 32 + hc * 4 + 0], hv.x, a0);
      a0 = dp2(wreg[0 * 32 + hc * 4 + 1], hv.y, a0);
      a0 = dp2(wreg[0 * 32 + hc * 4 + 2], hv.z, a0);
      a0 = dp2(wreg[0 * 32 + hc * 4 + 3], hv.w, a0);
      a1 = dp2(wreg[1 * 32 + hc * 4 + 0], hv.x, a1);
      a1 = dp2(wreg[1 * 32 + hc * 4 + 1], hv.y, a1);
      a1 = dp2(wreg[1 * 32 + hc * 4 + 2], hv.z, a1);
      a1 = dp2(wreg[1 * 32 + hc * 4 + 3], hv.w, a1);
      a2 = dp2(wreg[2 * 32 + hc * 4 + 0], hv.x, a2);
      a2 = dp2(wreg[2 * 32 + hc * 4 + 1], hv.y, a2);
      a2 = dp2(wreg[2 * 32 + hc * 4 + 2], hv.z, a2);
      a2 = dp2(wreg[2 * 32 + hc * 4 + 3], hv.w, a2);
      a3 = dp2(w3.x, hv.x, a3);
      a3 = dp2(w3.y, hv.y, a3);
      a3 = dp2(w3.z, hv.z, a3);
      a3 = dp2(w3.w, hv.w, a3);
    }
    // partials: pacc[s][r] — lane-consecutive r => conflict-free writes
    pacc[s * 512 + ib]       = a0;
    pacc[s * 512 + ib + 128] = a1;
    pacc[s * 512 + ib + 256] = a2;
    pacc[s * 512 + ib + 384] = a3;
    __syncthreads();

    if (tid < 512) {
      float pre = xpv + bh;
#pragma unroll
      for (int s2 = 0; s2 < 8; ++s2) pre += pacc[s2 * 512 + tid];  // conflict-free
      float h = tanhf(pre);
      xprow[t * HIDDEN + tid] = h;
      ((f16*)hh4)[tid] = (f16)h;
      if (t == SEQLEN - 1) hfin[(long long)b * HIDDEN + tid] = h;
    }
    __syncthreads();
  }
}

// ---------------------------------------------------------------------------
extern "C" void kernel_launch(void* const* d_in, const int* in_sizes, int n_in,
                              void* d_out, int out_size, void* d_ws, size_t ws_size,
                              hipStream_t stream) {
  const int*   tokens = (const int*)  d_in[0];
  const float* hidden = (const float*)d_in[1];
  const float* emb    = (const float*)d_in[2];
  const float* wih    = (const float*)d_in[3];
  const float* whh    = (const float*)d_in[4];
  const float* bih    = (const float*)d_in[5];
  const float* bhh    = (const float*)d_in[6];
  float* out = (float*)d_out;

  f16* emb16 = (f16*)d_ws;
  f16* wih16 = (f16*)((char*)d_ws + 32768000);
  f16* whh16 = (f16*)((char*)d_ws + 33292288);

  // Phase 0: convert emb/W_ih/W_hh to f16
  conv_f16_kernel<<<16512, 256, 0, stream>>>(emb, wih, whh, emb16, wih16, whh16);

  // Phase 1: x_proj into d_out (consumed in-place by phase 2)
  xproj_kernel<<<dim3(4, 256), 256, 0, stream>>>(tokens, emb16, wih16, bih, out);

  // Phase 2: recurrence. LDS = 1 KB h + 16 KB pacc + 128 KB W = 148,480 B
  const int LDSB = 1024 + 16384 + 131072;
  hipFuncSetAttribute((const void*)rnn_kernel,
                      hipFuncAttributeMaxDynamicSharedMemorySize, LDSB);
  rnn_kernel<<<BATCH, 1024, LDSB, stream>>>(
      whh16, bhh, hidden, out, out + (long long)BATCH * SEQLEN * HIDDEN);
}